// Round 7
// baseline (336.440 us; speedup 1.0000x reference)
//
#include <hip/hip_runtime.h>
#include <hip/hip_bf16.h>

#define B_    32
#define CIN   64
#define HW    56
#define COUT  128
#define M_    256
#define P_    576
#define L_    3136
#define N_    100352

typedef __hip_bfloat16 bf16;
typedef unsigned short u16;
typedef __attribute__((ext_vector_type(2))) unsigned short u16x2;
typedef __attribute__((ext_vector_type(8))) short bf16x8;
typedef __attribute__((ext_vector_type(8))) unsigned short u16x8;
typedef __attribute__((ext_vector_type(4))) float f32x4;

__device__ __forceinline__ float bits2f(u16 u){ return __uint_as_float(((unsigned)u) << 16); }
__device__ __forceinline__ u16 f2bf(float f){
  bf16 h = __float2bfloat16(f);
  return *(u16*)&h;
}
__device__ __forceinline__ void gload16(const void* g, void* l){
  __builtin_amdgcn_global_load_lds((const __attribute__((address_space(1))) void*)g,
                                   (__attribute__((address_space(3))) void*)l, 16, 0, 0);
}

// ---- K0: C -> Cb (bf16 [m][p]), Ct (bf16 [p][m]), b2; W -> Wb (bf16) -------
__global__ __launch_bounds__(256) void k0_prep(const float* __restrict__ C,
                                               const float* __restrict__ W,
                                               u16* __restrict__ Cb, u16* __restrict__ Ct,
                                               float* __restrict__ b2v, u16* __restrict__ Wb){
  __shared__ float red[4];
  const int t = threadIdx.x;
  const int bid = blockIdx.x;
  if (bid < M_){
    const int m = bid;
    float s = 0.f;
    for (int p = t; p < P_; p += 256){
      u16 h = f2bf(C[(size_t)m*P_ + p]);
      float vr = bits2f(h);
      s += vr*vr;
      Cb[(size_t)m*P_ + p] = h;
      Ct[(size_t)p*M_ + m] = h;
    }
    #pragma unroll
    for (int off = 32; off >= 1; off >>= 1) s += __shfl_xor(s, off);
    if ((t & 63) == 0) red[t >> 6] = s;
    __syncthreads();
    if (t == 0) b2v[m] = red[0] + red[1] + red[2] + red[3];
  } else {
    const int co = bid - M_;
    for (int q = t; q < P_; q += 256)
      Wb[(size_t)co*P_ + q] = f2bf(W[(size_t)co*P_ + q]);
  }
}

// ---- K1: unfold, tiled: block = (b,h); x window staged in LDS --------------
__global__ __launch_bounds__(256) void k1_unfold(const float* __restrict__ x,
                                                 u16* __restrict__ A,
                                                 float* __restrict__ a2v){
  __shared__ float xt[64*175 + 1];   // 64 ch x (3 rows x 58 cols), stride 175
  const int t = threadIdx.x;
  const int bid = blockIdx.x;
  const int b = bid / HW, h = bid % HW;

  // stage x window: coalesced along w
  for (int idx = t; idx < 64*174; idx += 256){
    const int c = idx / 174, rem = idx - c*174;
    const int r = rem / 58, wc = rem - r*58;
    const int iy = h + r - 1, ix = wc - 1;
    float v = 0.f;
    if ((unsigned)iy < (unsigned)HW && (unsigned)ix < (unsigned)HW)
      v = x[((size_t)b*CIN + c)*L_ + iy*HW + ix];
    xt[c*175 + r*58 + wc] = v;
  }
  __syncthreads();

  // A-write: lanes cover consecutive p (2 per lane), loop over 56 patches
  const int n0 = b*L_ + h*56;
  u16* Arow = A + (size_t)n0 * P_;
  #pragma unroll
  for (int k = 0; k < 2; ++k){
    const int pb = k*512 + t*2;
    if (pb < P_){
      const int c0 = pb/9,     rr0 = pb - c0*9;
      const int c1 = (pb+1)/9, rr1 = (pb+1) - c1*9;
      const float* s0 = &xt[c0*175 + (rr0/3)*58 + (rr0 - (rr0/3)*3)];
      const float* s1 = &xt[c1*175 + (rr1/3)*58 + (rr1 - (rr1/3)*3)];
      for (int w = 0; w < 56; ++w){
        u16x2 o = { f2bf(s0[w]), f2bf(s1[w]) };
        *(u16x2*)&Arow[(size_t)w*P_ + pb] = o;
      }
    }
  }

  // a2: wave per patch-subset, lane = channel
  const int wid = t >> 6, lane = t & 63;
  for (int w = wid; w < 56; w += 4){
    const float* src = &xt[lane*175 + w];
    float s = 0.f;
    #pragma unroll
    for (int r = 0; r < 3; ++r)
      #pragma unroll
      for (int dj = 0; dj < 3; ++dj){
        float vr = bits2f(f2bf(src[r*58 + dj]));
        s += vr*vr;
      }
    #pragma unroll
    for (int off = 32; off >= 1; off >>= 1) s += __shfl_xor(s, off);
    if (lane == 0) a2v[n0 + w] = s;
  }
}

// ---- K23: fused assign+transform. Block = 64 rows n. --------------------
//  P1: G = A*Cb^T (A: 3-deep LDS ring via global_load_lds, counted vmcnt;
//      Cb: direct L2->reg frags) + dist + softmax -> Sl (LDS)
//  P2: T = Sl*Ct (Ct: direct L2->reg frags), no barriers
//  F-write: two 288-p halves, Fl staging + skip-RMW into AF (in place on A)
__global__ __launch_bounds__(256, 2) void k23_fused(const u16* __restrict__ A,
    const u16* __restrict__ Cb, const u16* __restrict__ Ct,
    const float* __restrict__ a2v, const float* __restrict__ b2v,
    const float* __restrict__ temp_p, u16* __restrict__ AF){
  __shared__ __align__(16) char lds[72704];
  u16*   Sl  = (u16*)lds;             // 64 x 264 u16 = 33792 B (persistent)
  char*  R2  = lds + 33792;           // 38912 B region
  short* AlB = (short*)R2;            // 3 bufs x 64x32 shorts = 12288 B (phase 1)
  float* red = (float*)R2;            // 256 f (softmax; after Al reads done)
  u16*   Fl  = (u16*)R2;              // 64 x 296 u16 = 37888 B (F staging)

  const int t = threadIdx.x;
  const int lane = t & 63;
  const int wv = t >> 6;              // wave 0..3
  const int g  = lane >> 4;
  const int lr = lane & 15;
  const int n0 = blockIdx.x * 64;
  const int sw = (g ^ (lr & 3)) << 3;
  const float temp = *temp_p;

  // ================= phase 1: G = A * Cb^T =================
  f32x4 acc[4][4];
  #pragma unroll
  for (int i = 0; i < 4; ++i)
    #pragma unroll
    for (int j = 0; j < 4; ++j) acc[i][j] = (f32x4){0.f,0.f,0.f,0.f};

  const int arow = t >> 2, ach = t & 3;
  const int agch = ach ^ (arow & 3);
  const u16* Asrc = A + (size_t)(n0 + arow)*P_ + agch*8;

  // prologue: fill ring depth 2
  gload16(Asrc +  0, &AlB[0*2048 + t*8]);
  gload16(Asrc + 32, &AlB[1*2048 + t*8]);

  #pragma unroll
  for (int k = 0; k < 18; ++k){
    if (k + 2 < 18) gload16(Asrc + (k+2)*32, &AlB[((k+2)%3)*2048 + t*8]);
    if (k < 16)      asm volatile("s_waitcnt vmcnt(2)" ::: "memory");
    else if (k==16)  asm volatile("s_waitcnt vmcnt(1)" ::: "memory");
    else             asm volatile("s_waitcnt vmcnt(0)" ::: "memory");
    __builtin_amdgcn_s_barrier();
    __builtin_amdgcn_sched_barrier(0);
    const short* Alc = &AlB[(k%3)*2048];
    bf16x8 af[4], bb[4];
    #pragma unroll
    for (int i = 0; i < 4; ++i)
      af[i] = *(const bf16x8*)&Alc[(i*16 + lr)*32 + sw];
    #pragma unroll
    for (int j = 0; j < 4; ++j)
      bb[j] = *(const bf16x8*)(Cb + (size_t)(wv*64 + j*16 + lr)*P_ + k*32 + g*8);
    #pragma unroll
    for (int i = 0; i < 4; ++i)
      #pragma unroll
      for (int j = 0; j < 4; ++j)
        acc[i][j] = __builtin_amdgcn_mfma_f32_16x16x32_bf16(af[i], bb[j], acc[i][j], 0, 0, 0);
    __builtin_amdgcn_s_barrier();
    __builtin_amdgcn_sched_barrier(0);
  }

  // ---- softmax over all 256 m ----
  float a2r[4][4], b2r[4];
  #pragma unroll
  for (int i = 0; i < 4; ++i)
    #pragma unroll
    for (int r = 0; r < 4; ++r) a2r[i][r] = a2v[n0 + i*16 + g*4 + r];
  #pragma unroll
  for (int j = 0; j < 4; ++j) b2r[j] = b2v[wv*64 + j*16 + lr];

  float rmax[4][4];
  #pragma unroll
  for (int i = 0; i < 4; ++i)
    #pragma unroll
    for (int r = 0; r < 4; ++r) rmax[i][r] = -3.4e38f;

  #pragma unroll
  for (int i = 0; i < 4; ++i)
    #pragma unroll
    for (int j = 0; j < 4; ++j)
      #pragma unroll
      for (int r = 0; r < 4; ++r){
        float d2 = fmaxf(a2r[i][r] + b2r[j] - 2.f*acc[i][j][r], 1e-12f);
        float lg = -temp * sqrtf(d2);
        acc[i][j][r] = lg;
        rmax[i][r] = fmaxf(rmax[i][r], lg);
      }
  #pragma unroll
  for (int i = 0; i < 4; ++i)
    #pragma unroll
    for (int r = 0; r < 4; ++r){
      float v = rmax[i][r];
      v = fmaxf(v, __shfl_xor(v, 1));
      v = fmaxf(v, __shfl_xor(v, 2));
      v = fmaxf(v, __shfl_xor(v, 4));
      v = fmaxf(v, __shfl_xor(v, 8));
      rmax[i][r] = v;
    }
  __syncthreads();                 // phase-1 LDS reads done (red overlays AlB)
  if (lr == 0){
    #pragma unroll
    for (int i = 0; i < 4; ++i)
      #pragma unroll
      for (int r = 0; r < 4; ++r) red[wv*64 + i*16 + g*4 + r] = rmax[i][r];
  }
  __syncthreads();
  #pragma unroll
  for (int i = 0; i < 4; ++i)
    #pragma unroll
    for (int r = 0; r < 4; ++r){
      const int row = i*16 + g*4 + r;
      rmax[i][r] = fmaxf(fmaxf(red[row], red[64+row]), fmaxf(red[128+row], red[192+row]));
    }
  float rsum[4][4];
  #pragma unroll
  for (int i = 0; i < 4; ++i)
    #pragma unroll
    for (int r = 0; r < 4; ++r) rsum[i][r] = 0.f;
  #pragma unroll
  for (int i = 0; i < 4; ++i)
    #pragma unroll
    for (int j = 0; j < 4; ++j)
      #pragma unroll
      for (int r = 0; r < 4; ++r){
        float pe = __expf(acc[i][j][r] - rmax[i][r]);
        acc[i][j][r] = pe;
        rsum[i][r] += pe;
      }
  #pragma unroll
  for (int i = 0; i < 4; ++i)
    #pragma unroll
    for (int r = 0; r < 4; ++r){
      float v = rsum[i][r];
      v += __shfl_xor(v, 1);
      v += __shfl_xor(v, 2);
      v += __shfl_xor(v, 4);
      v += __shfl_xor(v, 8);
      rsum[i][r] = v;
    }
  __syncthreads();                 // rmax reads done
  if (lr == 0){
    #pragma unroll
    for (int i = 0; i < 4; ++i)
      #pragma unroll
      for (int r = 0; r < 4; ++r) red[wv*64 + i*16 + g*4 + r] = rsum[i][r];
  }
  __syncthreads();
  #pragma unroll
  for (int i = 0; i < 4; ++i)
    #pragma unroll
    for (int r = 0; r < 4; ++r){
      const int row = i*16 + g*4 + r;
      const float invr = 1.f / (red[row] + red[64+row] + red[128+row] + red[192+row]);
      #pragma unroll
      for (int j = 0; j < 4; ++j)
        Sl[(size_t)row*264 + wv*64 + j*16 + lr] = f2bf(acc[i][j][r] * invr);
    }
  __syncthreads();                 // Sl visible; R2 free

  // ================= phase 2: T = Sl * Ct (no barriers) =================
  const int p0q = wv * 144;        // wave's p-quarter
  f32x4 acc2[4][9];
  #pragma unroll
  for (int i = 0; i < 4; ++i)
    #pragma unroll
    for (int j = 0; j < 9; ++j) acc2[i][j] = (f32x4){0.f,0.f,0.f,0.f};

  for (int mc = 0; mc < 8; ++mc){
    bf16x8 af2[4];
    #pragma unroll
    for (int i = 0; i < 4; ++i)
      af2[i] = *(const bf16x8*)&Sl[(size_t)(i*16 + lr)*264 + mc*32 + g*8];
    #pragma unroll
    for (int j = 0; j < 9; ++j){
      bf16x8 bb = *(const bf16x8*)(Ct + (size_t)(p0q + j*16 + lr)*M_ + mc*32 + g*8);
      #pragma unroll
      for (int i = 0; i < 4; ++i)
        acc2[i][j] = __builtin_amdgcn_mfma_f32_16x16x32_bf16(af2[i], bb, acc2[i][j], 0, 0, 0);
    }
  }

  // ---- F write: two 288-p halves, skip-RMW coalesced into AF -------------
  const float inv = 1.f / (temp + 1.f);
  const float tscale = temp * inv;
  #pragma unroll
  for (int h = 0; h < 2; ++h){
    __syncthreads();               // Fl region free (prev reads done)
    if ((wv >> 1) == h){
      const int pbase = (wv & 1) * 144;
      #pragma unroll
      for (int i = 0; i < 4; ++i)
        #pragma unroll
        for (int j = 0; j < 9; ++j)
          #pragma unroll
          for (int r = 0; r < 4; ++r)
            Fl[(i*16 + g*4 + r)*296 + pbase + j*16 + lr] = f2bf(acc2[i][j][r] * tscale);
    }
    __syncthreads();
    #pragma unroll
    for (int e = 0; e < 9; ++e){
      const int v = t + e*256;     // 0..2303
      const int row = v / 36, col = (v - row*36) * 8;
      u16x8 tv = *(const u16x8*)&Fl[row*296 + col];
      u16* gp = AF + (size_t)(n0 + row)*P_ + h*288 + col;
      u16x8 av = *(const u16x8*)gp;
      u16x8 o;
      #pragma unroll
      for (int e2 = 0; e2 < 8; ++e2)
        o[e2] = f2bf(bits2f(tv[e2]) + bits2f(av[e2]) * inv);
      *(u16x8*)gp = o;
    }
  }
}

// ---- K4: MFMA GEMM out = Wb * F (+bias), mask fused into F staging ---------
// F viewed as [b][q][s] flat; B-tile transposed to [s][q] in LDS (stride 40).
__global__ __launch_bounds__(256) void k4_conv(const u16* __restrict__ F,
    const u16* __restrict__ Wb, const float* __restrict__ bias,
    float* __restrict__ out){
  __shared__ short Wl[128*32];    // 8 KB
  __shared__ short Fl[128*40];    // 10 KB, row stride 40 shorts (16B aligned)
  const int t = threadIdx.x;
  const int lane = t & 63;
  const int w = t >> 6;           // 0..3
  const int wn = w >> 1;          // co half
  const int ws = w & 1;           // s half
  const int g  = lane >> 4;
  const int lr = lane & 15;
  const int b  = blockIdx.y;
  const int s0 = blockIdx.x * 128;
  const int sw = (g ^ (lr & 3)) << 3;
  const u16* Fb = F + (size_t)b * ((size_t)P_ * L_);

  f32x4 acc[4][4];
  #pragma unroll
  for (int i = 0; i < 4; ++i)
    #pragma unroll
    for (int j = 0; j < 4; ++j) acc[i][j] = (f32x4){0.f,0.f,0.f,0.f};

  for (int q0 = 0; q0 < P_; q0 += 32){
    __syncthreads();
    #pragma unroll
    for (int e = 0; e < 2; ++e){
      const int c = t + e*256;
      const int r = c >> 2, ch = c & 3;
      gload16(Wb + (size_t)r*P_ + q0 + (ch ^ (r & 3))*8, &Wl[c*8]);
    }
    #pragma unroll
    for (int e = 0; e < 2; ++e){
      const int c = t + e*256;
      const int ql = c & 31, sch = c >> 5;
      const int q  = q0 + ql;
      const int sbase = s0 + sch*8;
      const int scl = (sbase < L_ - 8) ? sbase : (L_ - 8);
      u16x8 v = *(const u16x8*)(Fb + (size_t)q*L_ + scl);
      const int q3 = q/3;
      const bool kx0 = (q - q3*3) == 0;
      const bool ky0 = (q3 % 3) == 0;
      const int r0 = sbase % 56;
      #pragma unroll
      for (int u = 0; u < 8; ++u){
        const bool m0 = ky0 && (sbase + u) < 56;
        const bool m1 = kx0 && ((r0 + u) == 0 || (r0 + u) == 56);
        Fl[(sch*8 + u)*40 + ql] = (m0 || m1) ? (short)0 : (short)v[u];
      }
    }
    __syncthreads();
    bf16x8 af[4], bb[4];
    #pragma unroll
    for (int i = 0; i < 4; ++i)
      af[i] = *(const bf16x8*)&Wl[(wn*64 + i*16 + lr)*32 + sw];
    #pragma unroll
    for (int j = 0; j < 4; ++j)
      bb[j] = *(const bf16x8*)&Fl[(ws*64 + j*16 + lr)*40 + g*8];
    #pragma unroll
    for (int i = 0; i < 4; ++i)
      #pragma unroll
      for (int j = 0; j < 4; ++j)
        acc[i][j] = __builtin_amdgcn_mfma_f32_16x16x32_bf16(af[i], bb[j], acc[i][j], 0, 0, 0);
  }

  #pragma unroll
  for (int i = 0; i < 4; ++i)
    #pragma unroll
    for (int r = 0; r < 4; ++r){
      const int co = wn*64 + i*16 + g*4 + r;
      const float bv = bias[co];
      #pragma unroll
      for (int j = 0; j < 4; ++j){
        const int s = s0 + ws*64 + j*16 + lr;
        if (s < L_) out[((size_t)b*COUT + co)*L_ + s] = acc[i][j][r] + bv;
      }
    }
}

extern "C" void kernel_launch(void* const* d_in, const int* in_sizes, int n_in,
                              void* d_out, int out_size, void* d_ws, size_t ws_size,
                              hipStream_t stream){
  const float* x      = (const float*)d_in[0];
  const float* weight = (const float*)d_in[1];
  const float* bias   = (const float*)d_in[2];
  const float* cc     = (const float*)d_in[3];
  const float* temp_p = (const float*)d_in[4];
  float* out = (float*)d_out;

  char* ws = (char*)d_ws;
  u16*   A   = (u16*)(ws);                 // N*P bf16   = 115,605,504 B
  float* a2v = (float*)(ws + 166985728);   // N f32      =     401,408 B
  float* b2v = (float*)(ws + 167387136);   // 256 f32    =       1,024 B
  u16*   Cb  = (u16*)(ws + 167388160);     // 256x576 bf16 =   294,912 B
  u16*   Ct  = (u16*)(ws + 167683072);     // 576x256 bf16 =   294,912 B
  u16*   Wb  = (u16*)(ws + 167977984);     // 128x576 bf16 =   147,456 B

  k0_prep   <<<384,          256, 0, stream>>>(cc, weight, Cb, Ct, b2v, Wb);
  k1_unfold <<<B_*HW,        256, 0, stream>>>(x, A, a2v);
  k23_fused <<<N_/64,        256, 0, stream>>>(A, Cb, Ct, a2v, b2v, temp_p, A);
  k4_conv   <<<dim3(25, B_), 256, 0, stream>>>(A, Wb, bias, out);
}

// Round 8
// 305.467 us; speedup vs baseline: 1.1014x; 1.1014x over previous
//
#include <hip/hip_runtime.h>
#include <hip/hip_bf16.h>

#define B_    32
#define CIN   64
#define HW    56
#define COUT  128
#define M_    256
#define P_    576
#define L_    3136
#define N_    100352

typedef __hip_bfloat16 bf16;
typedef unsigned short u16;
typedef __attribute__((ext_vector_type(2))) unsigned short u16x2;
typedef __attribute__((ext_vector_type(8))) short bf16x8;
typedef __attribute__((ext_vector_type(8))) unsigned short u16x8;
typedef __attribute__((ext_vector_type(4))) float f32x4;

__device__ __forceinline__ float bits2f(u16 u){ return __uint_as_float(((unsigned)u) << 16); }
__device__ __forceinline__ u16 f2bf(float f){
  bf16 h = __float2bfloat16(f);
  return *(u16*)&h;
}
__device__ __forceinline__ void gload16(const void* g, void* l){
  __builtin_amdgcn_global_load_lds((const __attribute__((address_space(1))) void*)g,
                                   (__attribute__((address_space(3))) void*)l, 16, 0, 0);
}

// ---- K0: build fragment-major operand layouts + b2 -------------------------
// CbP[((wv*4+j)*18+k)*64 + lane] (16B unit) = Cb[m=wv*64+j*16+lr][p=k*32+g*8 ..+8]
// CtP[((q*9+j)*8+mc)*64 + lane]            = Ct[p=q*144+j*16+lr][m=mc*32+g*8 ..+8]
// WbP[((wn*4+i)*18+k)*64 + lane]           = Wb[co=wn*64+i*16+lr][q=k*32+g*8 ..+8]
__global__ __launch_bounds__(256) void k0_prep(const float* __restrict__ C,
                                               const float* __restrict__ W,
                                               u16* __restrict__ CbP, u16* __restrict__ CtP,
                                               float* __restrict__ b2v, u16* __restrict__ WbP){
  __shared__ float red[4];
  const int t = threadIdx.x;
  const int bid = blockIdx.x;
  if (bid < M_){
    const int m = bid;
    float s = 0.f;
    for (int p = t; p < P_; p += 256){
      float vr = bits2f(f2bf(C[(size_t)m*P_ + p]));
      s += vr*vr;
    }
    #pragma unroll
    for (int off = 32; off >= 1; off >>= 1) s += __shfl_xor(s, off);
    if ((t & 63) == 0) red[t >> 6] = s;
    __syncthreads();
    if (t == 0) b2v[m] = red[0] + red[1] + red[2] + red[3];
  } else if (bid < M_ + 72){
    const int u = (bid - M_)*256 + t;          // [0, 18432)
    const int f = u >> 6, lane = u & 63;
    const int g = lane >> 4, lr = lane & 15;
    const int k = f % 18, fj = f / 18;
    const int j = fj & 3, wvq = fj >> 2;
    const int m = wvq*64 + j*16 + lr;
    const int p = k*32 + g*8;
    u16x8 o;
    #pragma unroll
    for (int c = 0; c < 8; ++c) o[c] = f2bf(C[(size_t)m*P_ + p + c]);
    *(u16x8*)&CbP[(size_t)u*8] = o;
  } else if (bid < M_ + 144){
    const int u = (bid - M_ - 72)*256 + t;     // [0, 18432)
    const int f = u >> 6, lane = u & 63;
    const int g = lane >> 4, lr = lane & 15;
    const int mc = f & 7, fj = f >> 3;
    const int j = fj % 9, q = fj / 9;
    const int p = q*144 + j*16 + lr;
    const int m = mc*32 + g*8;
    u16x8 o;
    #pragma unroll
    for (int c = 0; c < 8; ++c) o[c] = f2bf(C[(size_t)(m + c)*P_ + p]);
    *(u16x8*)&CtP[(size_t)u*8] = o;
  } else {
    const int u = (bid - M_ - 144)*256 + t;    // [0, 9216)
    const int f = u >> 6, lane = u & 63;
    const int g = lane >> 4, lr = lane & 15;
    const int k = f % 18, fi = f / 18;
    const int i = fi & 3, wn = fi >> 2;
    const int co = wn*64 + i*16 + lr;
    const int q = k*32 + g*8;
    u16x8 o;
    #pragma unroll
    for (int c = 0; c < 8; ++c) o[c] = f2bf(W[(size_t)co*P_ + q + c]);
    *(u16x8*)&WbP[(size_t)u*8] = o;
  }
}

// ---- K1: unfold, tiled: block = (b,h); x window staged in LDS --------------
__global__ __launch_bounds__(256) void k1_unfold(const float* __restrict__ x,
                                                 u16* __restrict__ A,
                                                 float* __restrict__ a2v){
  __shared__ float xt[64*175 + 1];   // 64 ch x (3 rows x 58 cols), stride 175
  const int t = threadIdx.x;
  const int bid = blockIdx.x;
  const int b = bid / HW, h = bid % HW;

  for (int idx = t; idx < 64*174; idx += 256){
    const int c = idx / 174, rem = idx - c*174;
    const int r = rem / 58, wc = rem - r*58;
    const int iy = h + r - 1, ix = wc - 1;
    float v = 0.f;
    if ((unsigned)iy < (unsigned)HW && (unsigned)ix < (unsigned)HW)
      v = x[((size_t)b*CIN + c)*L_ + iy*HW + ix];
    xt[c*175 + r*58 + wc] = v;
  }
  __syncthreads();

  const int n0 = b*L_ + h*56;
  u16* Arow = A + (size_t)n0 * P_;
  #pragma unroll
  for (int k = 0; k < 2; ++k){
    const int pb = k*512 + t*2;
    if (pb < P_){
      const int c0 = pb/9,     rr0 = pb - c0*9;
      const int c1 = (pb+1)/9, rr1 = (pb+1) - c1*9;
      const float* s0 = &xt[c0*175 + (rr0/3)*58 + (rr0 - (rr0/3)*3)];
      const float* s1 = &xt[c1*175 + (rr1/3)*58 + (rr1 - (rr1/3)*3)];
      for (int w = 0; w < 56; ++w){
        u16x2 o = { f2bf(s0[w]), f2bf(s1[w]) };
        *(u16x2*)&Arow[(size_t)w*P_ + pb] = o;
      }
    }
  }

  const int wid = t >> 6, lane = t & 63;
  for (int w = wid; w < 56; w += 4){
    const float* src = &xt[lane*175 + w];
    float s = 0.f;
    #pragma unroll
    for (int r = 0; r < 3; ++r)
      #pragma unroll
      for (int dj = 0; dj < 3; ++dj){
        float vr = bits2f(f2bf(src[r*58 + dj]));
        s += vr*vr;
      }
    #pragma unroll
    for (int off = 32; off >= 1; off >>= 1) s += __shfl_xor(s, off);
    if (lane == 0) a2v[n0 + w] = s;
  }
}

// ---- K23: fused assign+transform. Block = 64 rows n. -----------------------
//  P1: G = A*CbP^T (A: 3-deep LDS ring, counted vmcnt; CbP: coalesced L2 frags,
//      software-pipelined 1 step ahead) + dist + softmax -> Sl (LDS)
//  P2: T = Sl*CtP (coalesced L2 frags, batch-9), no barriers
//  F-write: two 288-p halves, Fl staging + skip-RMW into AF (in place on A)
__global__ __launch_bounds__(256, 2) void k23_fused(const u16* __restrict__ A,
    const u16* __restrict__ CbP, const u16* __restrict__ CtP,
    const float* __restrict__ a2v, const float* __restrict__ b2v,
    const float* __restrict__ temp_p, u16* __restrict__ AF){
  __shared__ __align__(16) char lds[71680];
  u16*   Sl  = (u16*)lds;             // 64 x 264 u16 = 33792 B (persistent)
  char*  R2  = lds + 33792;           // 37888 B region
  short* AlB = (short*)R2;            // 3 bufs x 64x32 shorts = 12288 B (phase 1)
  float* red = (float*)R2;            // 256 f (softmax; after Al reads done)
  u16*   Fl  = (u16*)R2;              // 64 x 296 u16 = 37888 B (F staging)

  const int t = threadIdx.x;
  const int lane = t & 63;
  const int wv = t >> 6;              // wave 0..3
  const int g  = lane >> 4;
  const int lr = lane & 15;
  const int n0 = blockIdx.x * 64;
  const int sw = (g ^ (lr & 3)) << 3;
  const float temp = *temp_p;

  // ================= phase 1: G = A * Cb^T =================
  f32x4 acc[4][4];
  #pragma unroll
  for (int i = 0; i < 4; ++i)
    #pragma unroll
    for (int j = 0; j < 4; ++j) acc[i][j] = (f32x4){0.f,0.f,0.f,0.f};

  const int arow = t >> 2, ach = t & 3;
  const int agch = ach ^ (arow & 3);
  const u16* Asrc = A + (size_t)(n0 + arow)*P_ + agch*8;

  // prologue: fill A ring depth 2; load bb frags for k=0
  gload16(Asrc +  0, &AlB[0*2048 + t*8]);
  gload16(Asrc + 32, &AlB[1*2048 + t*8]);
  bf16x8 bbc[4], bbn[4];
  #pragma unroll
  for (int j = 0; j < 4; ++j)
    bbc[j] = *(const bf16x8*)(CbP + (((size_t)(wv*4 + j)*18 + 0)*64 + lane)*8);

  #pragma unroll
  for (int k = 0; k < 18; ++k){
    if (k + 2 < 18) gload16(Asrc + (k+2)*32, &AlB[((k+2)%3)*2048 + t*8]);
    if (k < 16)      asm volatile("s_waitcnt vmcnt(2)" ::: "memory");
    else if (k==16)  asm volatile("s_waitcnt vmcnt(1)" ::: "memory");
    else             asm volatile("s_waitcnt vmcnt(0)" ::: "memory");
    __builtin_amdgcn_s_barrier();
    __builtin_amdgcn_sched_barrier(0);
    const short* Alc = &AlB[(k%3)*2048];
    bf16x8 af[4];
    #pragma unroll
    for (int i = 0; i < 4; ++i)
      af[i] = *(const bf16x8*)&Alc[(i*16 + lr)*32 + sw];
    if (k + 1 < 18){
      #pragma unroll
      for (int j = 0; j < 4; ++j)
        bbn[j] = *(const bf16x8*)(CbP + (((size_t)(wv*4 + j)*18 + (k+1))*64 + lane)*8);
    }
    #pragma unroll
    for (int i = 0; i < 4; ++i)
      #pragma unroll
      for (int j = 0; j < 4; ++j)
        acc[i][j] = __builtin_amdgcn_mfma_f32_16x16x32_bf16(af[i], bbc[j], acc[i][j], 0, 0, 0);
    __builtin_amdgcn_s_barrier();
    __builtin_amdgcn_sched_barrier(0);
    if (k + 1 < 18){
      #pragma unroll
      for (int j = 0; j < 4; ++j) bbc[j] = bbn[j];
    }
  }

  // ---- softmax over all 256 m ----
  float a2r[4][4], b2r[4];
  #pragma unroll
  for (int i = 0; i < 4; ++i)
    #pragma unroll
    for (int r = 0; r < 4; ++r) a2r[i][r] = a2v[n0 + i*16 + g*4 + r];
  #pragma unroll
  for (int j = 0; j < 4; ++j) b2r[j] = b2v[wv*64 + j*16 + lr];

  float rmax[4][4];
  #pragma unroll
  for (int i = 0; i < 4; ++i)
    #pragma unroll
    for (int r = 0; r < 4; ++r) rmax[i][r] = -3.4e38f;

  #pragma unroll
  for (int i = 0; i < 4; ++i)
    #pragma unroll
    for (int j = 0; j < 4; ++j)
      #pragma unroll
      for (int r = 0; r < 4; ++r){
        float d2 = fmaxf(a2r[i][r] + b2r[j] - 2.f*acc[i][j][r], 1e-12f);
        float lg = -temp * sqrtf(d2);
        acc[i][j][r] = lg;
        rmax[i][r] = fmaxf(rmax[i][r], lg);
      }
  #pragma unroll
  for (int i = 0; i < 4; ++i)
    #pragma unroll
    for (int r = 0; r < 4; ++r){
      float v = rmax[i][r];
      v = fmaxf(v, __shfl_xor(v, 1));
      v = fmaxf(v, __shfl_xor(v, 2));
      v = fmaxf(v, __shfl_xor(v, 4));
      v = fmaxf(v, __shfl_xor(v, 8));
      rmax[i][r] = v;
    }
  __syncthreads();                 // phase-1 LDS reads done (red overlays AlB)
  if (lr == 0){
    #pragma unroll
    for (int i = 0; i < 4; ++i)
      #pragma unroll
      for (int r = 0; r < 4; ++r) red[wv*64 + i*16 + g*4 + r] = rmax[i][r];
  }
  __syncthreads();
  #pragma unroll
  for (int i = 0; i < 4; ++i)
    #pragma unroll
    for (int r = 0; r < 4; ++r){
      const int row = i*16 + g*4 + r;
      rmax[i][r] = fmaxf(fmaxf(red[row], red[64+row]), fmaxf(red[128+row], red[192+row]));
    }
  float rsum[4][4];
  #pragma unroll
  for (int i = 0; i < 4; ++i)
    #pragma unroll
    for (int r = 0; r < 4; ++r) rsum[i][r] = 0.f;
  #pragma unroll
  for (int i = 0; i < 4; ++i)
    #pragma unroll
    for (int j = 0; j < 4; ++j)
      #pragma unroll
      for (int r = 0; r < 4; ++r){
        float pe = __expf(acc[i][j][r] - rmax[i][r]);
        acc[i][j][r] = pe;
        rsum[i][r] += pe;
      }
  #pragma unroll
  for (int i = 0; i < 4; ++i)
    #pragma unroll
    for (int r = 0; r < 4; ++r){
      float v = rsum[i][r];
      v += __shfl_xor(v, 1);
      v += __shfl_xor(v, 2);
      v += __shfl_xor(v, 4);
      v += __shfl_xor(v, 8);
      rsum[i][r] = v;
    }
  __syncthreads();                 // rmax reads done
  if (lr == 0){
    #pragma unroll
    for (int i = 0; i < 4; ++i)
      #pragma unroll
      for (int r = 0; r < 4; ++r) red[wv*64 + i*16 + g*4 + r] = rsum[i][r];
  }
  __syncthreads();
  #pragma unroll
  for (int i = 0; i < 4; ++i)
    #pragma unroll
    for (int r = 0; r < 4; ++r){
      const int row = i*16 + g*4 + r;
      const float invr = 1.f / (red[row] + red[64+row] + red[128+row] + red[192+row]);
      #pragma unroll
      for (int j = 0; j < 4; ++j)
        Sl[(size_t)row*264 + wv*64 + j*16 + lr] = f2bf(acc[i][j][r] * invr);
    }
  __syncthreads();                 // Sl visible; R2 free

  // ========== phase 2: T = Sl * Ct (no barriers, batch frag loads) ==========
  f32x4 acc2[4][9];
  #pragma unroll
  for (int i = 0; i < 4; ++i)
    #pragma unroll
    for (int j = 0; j < 9; ++j) acc2[i][j] = (f32x4){0.f,0.f,0.f,0.f};

  for (int mc = 0; mc < 8; ++mc){
    bf16x8 af2[4], bb2[9];
    #pragma unroll
    for (int i = 0; i < 4; ++i)
      af2[i] = *(const bf16x8*)&Sl[(size_t)(i*16 + lr)*264 + mc*32 + g*8];
    #pragma unroll
    for (int j = 0; j < 9; ++j)
      bb2[j] = *(const bf16x8*)(CtP + (((size_t)(wv*9 + j)*8 + mc)*64 + lane)*8);
    #pragma unroll
    for (int j = 0; j < 9; ++j)
      #pragma unroll
      for (int i = 0; i < 4; ++i)
        acc2[i][j] = __builtin_amdgcn_mfma_f32_16x16x32_bf16(af2[i], bb2[j], acc2[i][j], 0, 0, 0);
  }

  // ---- F write: two 288-p halves, skip-RMW coalesced into AF -------------
  const float inv = 1.f / (temp + 1.f);
  const float tscale = temp * inv;
  #pragma unroll
  for (int h = 0; h < 2; ++h){
    __syncthreads();               // Fl region free (prev reads done)
    if ((wv >> 1) == h){
      const int pbase = (wv & 1) * 144;
      #pragma unroll
      for (int i = 0; i < 4; ++i)
        #pragma unroll
        for (int j = 0; j < 9; ++j)
          #pragma unroll
          for (int r = 0; r < 4; ++r)
            Fl[(i*16 + g*4 + r)*296 + pbase + j*16 + lr] = f2bf(acc2[i][j][r] * tscale);
    }
    __syncthreads();
    #pragma unroll
    for (int e = 0; e < 9; ++e){
      const int v = t + e*256;     // 0..2303
      const int row = v / 36, col = (v - row*36) * 8;
      u16x8 tv = *(const u16x8*)&Fl[row*296 + col];
      u16* gp = AF + (size_t)(n0 + row)*P_ + h*288 + col;
      u16x8 av = *(const u16x8*)gp;
      u16x8 o;
      #pragma unroll
      for (int e2 = 0; e2 < 8; ++e2)
        o[e2] = f2bf(bits2f(tv[e2]) + bits2f(av[e2]) * inv);
      *(u16x8*)gp = o;
    }
  }
}

// ---- K4: MFMA GEMM out = WbP * F (+bias), mask fused into F staging --------
// F viewed as [b][q][s] flat; B-tile transposed to [s][q] in LDS (stride 40).
__global__ __launch_bounds__(256) void k4_conv(const u16* __restrict__ F,
    const u16* __restrict__ WbP, const float* __restrict__ bias,
    float* __restrict__ out){
  __shared__ short Fl[128*40];    // 10 KB, row stride 40 shorts (16B aligned)
  const int t = threadIdx.x;
  const int lane = t & 63;
  const int w = t >> 6;           // 0..3
  const int wn = w >> 1;          // co half
  const int ws = w & 1;           // s half
  const int g  = lane >> 4;
  const int lr = lane & 15;
  const int b  = blockIdx.y;
  const int s0 = blockIdx.x * 128;
  const u16* Fb = F + (size_t)b * ((size_t)P_ * L_);

  f32x4 acc[4][4];
  #pragma unroll
  for (int i = 0; i < 4; ++i)
    #pragma unroll
    for (int j = 0; j < 4; ++j) acc[i][j] = (f32x4){0.f,0.f,0.f,0.f};

  for (int step = 0; step < 18; ++step){
    const int q0 = step * 32;
    __syncthreads();
    #pragma unroll
    for (int e = 0; e < 2; ++e){
      const int c = t + e*256;
      const int ql = c & 31, sch = c >> 5;
      const int q  = q0 + ql;
      const int sbase = s0 + sch*8;
      const int scl = (sbase < L_ - 8) ? sbase : (L_ - 8);
      u16x8 v = *(const u16x8*)(Fb + (size_t)q*L_ + scl);
      const int q3 = q/3;
      const bool kx0 = (q - q3*3) == 0;
      const bool ky0 = (q3 % 3) == 0;
      const int r0 = sbase % 56;
      #pragma unroll
      for (int u = 0; u < 8; ++u){
        const bool m0 = ky0 && (sbase + u) < 56;
        const bool m1 = kx0 && ((r0 + u) == 0 || (r0 + u) == 56);
        Fl[(sch*8 + u)*40 + ql] = (m0 || m1) ? (short)0 : (short)v[u];
      }
    }
    __syncthreads();
    bf16x8 af[4], bb[4];
    #pragma unroll
    for (int i = 0; i < 4; ++i)
      af[i] = *(const bf16x8*)(WbP + (((size_t)(wn*4 + i)*18 + step)*64 + lane)*8);
    #pragma unroll
    for (int j = 0; j < 4; ++j)
      bb[j] = *(const bf16x8*)&Fl[(ws*64 + j*16 + lr)*40 + g*8];
    #pragma unroll
    for (int i = 0; i < 4; ++i)
      #pragma unroll
      for (int j = 0; j < 4; ++j)
        acc[i][j] = __builtin_amdgcn_mfma_f32_16x16x32_bf16(af[i], bb[j], acc[i][j], 0, 0, 0);
  }

  #pragma unroll
  for (int i = 0; i < 4; ++i)
    #pragma unroll
    for (int r = 0; r < 4; ++r){
      const int co = wn*64 + i*16 + g*4 + r;
      const float bv = bias[co];
      #pragma unroll
      for (int j = 0; j < 4; ++j){
        const int s = s0 + ws*64 + j*16 + lr;
        if (s < L_) out[((size_t)b*COUT + co)*L_ + s] = acc[i][j][r] + bv;
      }
    }
}

extern "C" void kernel_launch(void* const* d_in, const int* in_sizes, int n_in,
                              void* d_out, int out_size, void* d_ws, size_t ws_size,
                              hipStream_t stream){
  const float* x      = (const float*)d_in[0];
  const float* weight = (const float*)d_in[1];
  const float* bias   = (const float*)d_in[2];
  const float* cc     = (const float*)d_in[3];
  const float* temp_p = (const float*)d_in[4];
  float* out = (float*)d_out;

  char* ws = (char*)d_ws;
  u16*   A   = (u16*)(ws);                 // N*P bf16   = 115,605,504 B
  float* a2v = (float*)(ws + 166985728);   // N f32      =     401,408 B
  float* b2v = (float*)(ws + 167387136);   // 256 f32    =       1,024 B
  u16*   CbP = (u16*)(ws + 167388160);     // 294,912 B (frag-major Cb)
  u16*   CtP = (u16*)(ws + 167683072);     // 294,912 B (frag-major Ct)
  u16*   WbP = (u16*)(ws + 167977984);     // 147,456 B (frag-major Wb)

  k0_prep   <<<436,          256, 0, stream>>>(cc, weight, CbP, CtP, b2v, WbP);
  k1_unfold <<<B_*HW,        256, 0, stream>>>(x, A, a2v);
  k23_fused <<<N_/64,        256, 0, stream>>>(A, CbP, CtP, a2v, b2v, temp_p, A);
  k4_conv   <<<dim3(25, B_), 256, 0, stream>>>(A, WbP, bias, out);
}